// Round 1
// baseline (269.280 us; speedup 1.0000x reference)
//
#include <hip/hip_runtime.h>

// AmplitudeEncoder: out[b,i,j] = s[b,i]*s[b,j], s = L2-normalized x padded to D.
// B=64, F=784, D=1001. Output 64*1001*1001 fp32 = 256.5 MB -> HBM-write-bound.

#define BATCH 64
#define F 784
#define D 1001
#define DD (D * D)              // 1002001
#define TOTAL (BATCH * DD)      // 64128064 (divisible by 4)
#define TOTAL4 (TOTAL / 4)      // 16032016

typedef float vfloat4 __attribute__((ext_vector_type(4)));

// ---------------- Kernel 1: per-batch normalization -> d_ws ----------------
__global__ __launch_bounds__(256) void amp_norm_kernel(
    const float* __restrict__ x, float* __restrict__ s) {
  const int b = blockIdx.x;
  const int t = threadIdx.x;
  const float* xb = x + b * F;

  // 784 = 3*256 + 16: each thread holds up to 4 values
  float v0 = (t < F)       ? xb[t]       : 0.f;
  float v1 = (t + 256 < F) ? xb[t + 256] : 0.f;
  float v2 = (t + 512 < F) ? xb[t + 512] : 0.f;
  float v3 = (t + 768 < F) ? xb[t + 768] : 0.f;

  float sum = v0 * v0 + v1 * v1 + v2 * v2 + v3 * v3;

  // wave64 butterfly reduce
  #pragma unroll
  for (int off = 32; off > 0; off >>= 1)
    sum += __shfl_down(sum, off, 64);

  __shared__ float wsum[4];
  __shared__ float inv_s;
  const int wave = t >> 6;
  const int lane = t & 63;
  if (lane == 0) wsum[wave] = sum;
  __syncthreads();
  if (t == 0) {
    float tot = wsum[0] + wsum[1] + wsum[2] + wsum[3];
    inv_s = 1.0f / sqrtf(tot);
  }
  __syncthreads();
  const float inv = inv_s;

  float* sb = s + b * F;
  if (t < F)       sb[t]       = v0 * inv;
  if (t + 256 < F) sb[t + 256] = v1 * inv;
  if (t + 512 < F) sb[t + 512] = v2 * inv;
  if (t + 768 < F) sb[t + 768] = v3 * inv;
}

// ---------------- Kernel 2: outer-product write (BW-bound) ----------------
__global__ __launch_bounds__(256) void amp_outer_kernel(
    const float* __restrict__ s, float* __restrict__ out) {
  const unsigned int f4 = blockIdx.x * 256u + threadIdx.x;
  if (f4 >= (unsigned int)TOTAL4) return;
  const unsigned int f = f4 * 4u;

  // decompose flat index (compiler emits magic-mul for const divisors)
  unsigned int bb = f / (unsigned int)DD;
  unsigned int rem = f - bb * (unsigned int)DD;
  unsigned int ii = rem / (unsigned int)D;
  unsigned int jj = rem - ii * (unsigned int)D;

  // row value (0 outside the F x F block)
  float r = (ii < F) ? s[bb * F + ii] : 0.f;

  float vals[4];
  #pragma unroll
  for (int k = 0; k < 4; ++k) {
    float c = (jj < F) ? s[bb * F + jj] : 0.f;
    vals[k] = r * c;  // r==0 covers ii>=F rows
    // advance one column; handle row / batch wrap (rare: 1 in ~250 chunks)
    ++jj;
    if (jj == D) {
      jj = 0;
      ++ii;
      if (ii == D) { ii = 0; ++bb; }
      r = (ii < F) ? s[bb * F + ii] : 0.f;
    }
  }

  vfloat4 o = {vals[0], vals[1], vals[2], vals[3]};
  __builtin_nontemporal_store(o, (vfloat4*)(out + f));
}

extern "C" void kernel_launch(void* const* d_in, const int* in_sizes, int n_in,
                              void* d_out, int out_size, void* d_ws, size_t ws_size,
                              hipStream_t stream) {
  const float* x = (const float*)d_in[0];
  float* out = (float*)d_out;
  float* s = (float*)d_ws;  // 64*784 fp32 = 200 KB scratch

  amp_norm_kernel<<<BATCH, 256, 0, stream>>>(x, s);
  amp_outer_kernel<<<(TOTAL4 + 255) / 256, 256, 0, stream>>>(s, out);
}

// Round 2
// 258.668 us; speedup vs baseline: 1.0410x; 1.0410x over previous
//
#include <hip/hip_runtime.h>

// AmplitudeEncoder: out[b,i,j] = s[b,i]*s[b,j], s = L2-normalized x padded to D.
// B=64, F=784, D=1001. Output 64*1001*1001 fp32 = 256.5 MB -> HBM-write-bound.
// Floor: 256.5 MB / 6.35 TB/s (measured fill rate on this box) = ~40 us.

#define BATCH 64
#define F 784
#define D 1001
#define DDU 1002001u            // D*D
#define TOTAL4 16032016u        // BATCH*D*D/4 (divides exactly)

typedef float vfloat4 __attribute__((ext_vector_type(4)));

// ---------------- Kernel 1: per-batch normalization -> d_ws ----------------
__global__ __launch_bounds__(256) void amp_norm_kernel(
    const float* __restrict__ x, float* __restrict__ s) {
  const int b = blockIdx.x;
  const int t = threadIdx.x;
  const float* xb = x + b * F;

  // 784 = 3*256 + 16: each thread holds up to 4 values
  float v0 = (t < F)       ? xb[t]       : 0.f;
  float v1 = (t + 256 < F) ? xb[t + 256] : 0.f;
  float v2 = (t + 512 < F) ? xb[t + 512] : 0.f;
  float v3 = (t + 768 < F) ? xb[t + 768] : 0.f;

  float sum = v0 * v0 + v1 * v1 + v2 * v2 + v3 * v3;

  // wave64 reduce
  #pragma unroll
  for (int off = 32; off > 0; off >>= 1)
    sum += __shfl_down(sum, off, 64);

  __shared__ float wsum[4];
  __shared__ float inv_s;
  const int wave = t >> 6;
  const int lane = t & 63;
  if (lane == 0) wsum[wave] = sum;
  __syncthreads();
  if (t == 0) {
    float tot = wsum[0] + wsum[1] + wsum[2] + wsum[3];
    inv_s = 1.0f / sqrtf(tot);
  }
  __syncthreads();
  const float inv = inv_s;

  float* sb = s + b * F;
  if (t < F)       sb[t]       = v0 * inv;
  if (t + 256 < F) sb[t + 256] = v1 * inv;
  if (t + 512 < F) sb[t + 768 - 256] = v2 * inv;   // t+512
  if (t + 768 < F) sb[t + 768] = v3 * inv;
}

// ---------------- Kernel 2: outer-product write (BW-bound) ----------------
// Grid-stride, fill-kernel-shaped: few blocks, many chunks/thread, plain
// stores. Each iteration: 1 float4 store + ~12 VALU index math + 4 L1-hot
// scalar reads of s.
__global__ __launch_bounds__(256) void amp_outer_kernel(
    const float* __restrict__ s, float* __restrict__ out) {
  const unsigned stride = gridDim.x * 256u;
  for (unsigned f4 = blockIdx.x * 256u + threadIdx.x; f4 < TOTAL4;
       f4 += stride) {
    const unsigned f = f4 * 4u;
    // decompose flat index (magic-mul for const divisors)
    unsigned bb = f / DDU;
    unsigned rem = f - bb * DDU;
    unsigned ii = rem / (unsigned)D;
    unsigned jj = rem - ii * (unsigned)D;

    float r = (ii < F) ? s[bb * F + ii] : 0.f;

    float vals[4];
    #pragma unroll
    for (int k = 0; k < 4; ++k) {
      float c = (jj < F) ? s[bb * F + jj] : 0.f;
      vals[k] = r * c;  // r==0 covers ii>=F rows
      ++jj;
      if (jj == (unsigned)D) {   // row wrap: ~1 in 250 chunks
        jj = 0;
        ++ii;
        if (ii == (unsigned)D) { ii = 0; ++bb; }
        r = (ii < F) ? s[bb * F + ii] : 0.f;
      }
    }

    vfloat4 o = {vals[0], vals[1], vals[2], vals[3]};
    *(vfloat4*)(out + f) = o;
  }
}

extern "C" void kernel_launch(void* const* d_in, const int* in_sizes, int n_in,
                              void* d_out, int out_size, void* d_ws, size_t ws_size,
                              hipStream_t stream) {
  const float* x = (const float*)d_in[0];
  float* out = (float*)d_out;
  float* s = (float*)d_ws;  // 64*784 fp32 = 200 KB scratch

  amp_norm_kernel<<<BATCH, 256, 0, stream>>>(x, s);
  // 4096 blocks * 256 thr = 1M threads, ~15.3 float4 chunks each
  amp_outer_kernel<<<4096, 256, 0, stream>>>(s, out);
}

// Round 3
// 254.411 us; speedup vs baseline: 1.0584x; 1.0167x over previous
//
#include <hip/hip_runtime.h>

// AmplitudeEncoder: out[b,i,j] = s[b,i]*s[b,j], s = L2-normalized x padded to D.
// B=64, F=784, D=1001. Output 64*1001*1001 fp32 = 256.5 MB -> HBM-write-bound.
// Floor: 256.5 MB / 6.6 TB/s (measured fill rate on this box) = ~39 us.
//
// R3 structure: zero global loads in the hot loop. Each block stages its
// batch's s_b into LDS with 4 phase-shifted copies so any column quad
// s[j..j+3] is ONE aligned ds_read_b128. Stores are flat 16B-aligned chunks.

#define BATCH 64
#define F 784
#define D 1001u
#define DD 1002001u   // D*D (odd -> batch bases are only dword-aligned)
#define NB 16         // sub-blocks per batch; grid = 64*NB = 1024 blocks
#define LDSW 1008     // padded copy width (>=1004, multiple of 4)

typedef float vfloat4 __attribute__((ext_vector_type(4)));

// ---------------- Kernel 1: per-batch normalization -> d_ws ----------------
__global__ __launch_bounds__(256) void amp_norm_kernel(
    const float* __restrict__ x, float* __restrict__ s) {
  const int b = blockIdx.x;
  const int t = threadIdx.x;
  const float* xb = x + b * F;

  float v0 = (t < F)       ? xb[t]       : 0.f;
  float v1 = (t + 256 < F) ? xb[t + 256] : 0.f;
  float v2 = (t + 512 < F) ? xb[t + 512] : 0.f;
  float v3 = (t + 768 < F) ? xb[t + 768] : 0.f;

  float sum = v0 * v0 + v1 * v1 + v2 * v2 + v3 * v3;

  #pragma unroll
  for (int off = 32; off > 0; off >>= 1)
    sum += __shfl_down(sum, off, 64);

  __shared__ float wsum[4];
  __shared__ float inv_s;
  const int wave = t >> 6;
  const int lane = t & 63;
  if (lane == 0) wsum[wave] = sum;
  __syncthreads();
  if (t == 0) {
    float tot = wsum[0] + wsum[1] + wsum[2] + wsum[3];
    inv_s = 1.0f / sqrtf(tot);
  }
  __syncthreads();
  const float inv = inv_s;

  float* sb = s + b * F;
  if (t < F)       sb[t]       = v0 * inv;
  if (t + 256 < F) sb[t + 256] = v1 * inv;
  if (t + 512 < F) sb[t + 512] = v2 * inv;
  if (t + 768 < F) sb[t + 768] = v3 * inv;
}

// ---------------- Kernel 2: outer-product write (HBM-write-bound) ----------
__global__ __launch_bounds__(256) void amp_outer_kernel(
    const float* __restrict__ s, float* __restrict__ out) {
  __shared__ float lds[4 * LDSW];   // 4 phase-shifted padded copies, 16.1 KB
  const unsigned bidx = blockIdx.x;
  const unsigned b  = bidx & 63u;   // batch
  const unsigned nb = bidx >> 6;    // sub-block 0..NB-1
  const unsigned t  = threadIdx.x;

  // stage copy0 = s_b padded with zeros to LDSW
  const float* sb = s + b * F;
  for (unsigned q = t; q < LDSW; q += 256u)
    lds[q] = (q < F) ? sb[q] : 0.f;
  __syncthreads();
  // shifted copies: copy_p[q] = s_pad[q+p]  (p=1..3)
  for (unsigned q = t; q < LDSW; q += 256u) {
    #pragma unroll
    for (unsigned p = 1; p < 4; ++p)
      lds[p * LDSW + q] = (q + p < LDSW) ? lds[q + p] : 0.f;
  }
  __syncthreads();

  const unsigned base = b * DD;            // dword base of this batch
  const unsigned c_lo = (base + 3u) >> 2;  // first full 16B chunk
  const unsigned c_hi = (base + DD) >> 2;  // one past last full chunk
  const unsigned nch  = c_hi - c_lo;
  const unsigned per  = (nch + (unsigned)NB - 1u) / (unsigned)NB;
  unsigned c     = c_lo + nb * per + t;
  unsigned c_end = c_lo + nb * per + per;
  if (c_end > c_hi) c_end = c_hi;

  for (; c < c_end; c += 256u) {
    const unsigned o = 4u * c - base;      // dword offset within batch
    const unsigned i = o / 1001u;          // row (magic-mul div)
    const unsigned j = o - i * 1001u;      // col of first dword
    vfloat4 vals;
    if (j <= 997u) {                       // chunk stays inside row i
      const float r = lds[i];              // 0 for pad rows (i>=784)
      if (r != 0.f && j < 784u) {
        const unsigned p = j & 3u;
        const unsigned m = j & ~3u;
        vfloat4 c4 = *(const vfloat4*)(lds + p * LDSW + m);  // ds_read_b128
        vals = c4 * r;
      } else {
        vals = (vfloat4){0.f, 0.f, 0.f, 0.f};
      }
    } else {                               // row-wrap chunk (~0.3%)
      float v[4];
      #pragma unroll
      for (unsigned k = 0; k < 4u; ++k) {
        unsigned jk = j + k;
        unsigned ik = i;
        if (jk >= 1001u) { jk -= 1001u; ik += 1u; }
        v[k] = lds[ik] * lds[jk];
      }
      vals = (vfloat4){v[0], v[1], v[2], v[3]};
    }
    *(vfloat4*)(out + 4u * c) = vals;
  }

  // batch-boundary scalar dwords (DD odd -> up to 3 head + 3 tail per batch)
  if (nb == 0u) {
    if (t == 0u) {
      const unsigned hb = (4u - (b & 3u)) & 3u;   // head dwords: row 0, cols 0..hb-1
      const float r0 = lds[0];
      for (unsigned k = 0; k < hb; ++k)
        out[base + k] = r0 * lds[k];
    } else if (t == 1u) {
      const unsigned tb = (b + 1u) & 3u;          // tail dwords: row 1000 (zero row)
      for (unsigned k = 0; k < tb; ++k)
        out[4u * c_hi + k] = 0.f;
    }
  }
}

extern "C" void kernel_launch(void* const* d_in, const int* in_sizes, int n_in,
                              void* d_out, int out_size, void* d_ws, size_t ws_size,
                              hipStream_t stream) {
  const float* x = (const float*)d_in[0];
  float* out = (float*)d_out;
  float* s = (float*)d_ws;  // 64*784 fp32 = 200 KB scratch

  amp_norm_kernel<<<BATCH, 256, 0, stream>>>(x, s);
  amp_outer_kernel<<<BATCH * NB, 256, 0, stream>>>(s, out);
}

// Round 4
// 248.556 us; speedup vs baseline: 1.0834x; 1.0236x over previous
//
#include <hip/hip_runtime.h>

// AmplitudeEncoder: out[b,i,j] = s[b,i]*s[b,j], s = L2-normalized x padded to D.
// B=64, F=784, D=1001. Output 64*1001*1001 fp32 = 256.5 MB -> HBM-write-bound.
// Write floor: 256.5 MB / 6.5 TB/s = ~40 us. Harness re-poison fills (d_ws
// 1.026 GB ~155 us + d_out 256 MB ~40 us) dominate dur_us; total floor ~240.
//
// R4: single fused kernel. Each block recomputes its batch's norm (x_b is
// 3.1 KB, L2-hot; redundant across 32 blocks/batch but free), stages 4
// phase-shifted LDS copies of s_b so any column quad is one ds_read_b128,
// then streams 16B-aligned chunk stores. No d_ws use, one launch.

#define BATCH 64
#define F 784
#define D 1001u
#define DD 1002001u   // D*D (odd -> batch bases are only dword-aligned)
#define NB 32         // sub-blocks per batch; grid = 64*NB = 2048 blocks
#define LDSW 1008     // padded copy width (>=1004, multiple of 4)

typedef float vfloat4 __attribute__((ext_vector_type(4)));

__global__ __launch_bounds__(256) void amp_fused_kernel(
    const float* __restrict__ x, float* __restrict__ out) {
  __shared__ float lds[4 * LDSW];   // 4 phase-shifted padded copies, 16.1 KB
  __shared__ float wsum[4];
  __shared__ float inv_s;

  const unsigned bidx = blockIdx.x;
  const unsigned b  = bidx & 63u;   // batch
  const unsigned nb = bidx >> 6;    // sub-block 0..NB-1
  const unsigned t  = threadIdx.x;

  // ---- per-block norm of x_b (deterministic: identical across sub-blocks)
  const float* xb = x + b * F;
  const float v0 = xb[t];                              // t < 784 always
  const float v1 = xb[t + 256];
  const float v2 = xb[t + 512];
  const float v3 = (t + 768 < F) ? xb[t + 768] : 0.f;

  float sum = v0 * v0 + v1 * v1 + v2 * v2 + v3 * v3;
  #pragma unroll
  for (int off = 32; off > 0; off >>= 1)
    sum += __shfl_down(sum, off, 64);
  if ((t & 63u) == 0u) wsum[t >> 6] = sum;
  __syncthreads();
  if (t == 0) inv_s = 1.0f / sqrtf(wsum[0] + wsum[1] + wsum[2] + wsum[3]);
  __syncthreads();
  const float inv = inv_s;

  // ---- stage copy0 = normalized s_b, zero-padded to LDSW
  lds[t]        = v0 * inv;
  lds[t + 256]  = v1 * inv;
  lds[t + 512]  = v2 * inv;
  if (t + 768 < LDSW) lds[t + 768] = (t + 768 < F) ? v3 * inv : 0.f;
  __syncthreads();
  // shifted copies: copy_p[q] = s_pad[q+p]  (p=1..3)
  for (unsigned q = t; q < LDSW; q += 256u) {
    #pragma unroll
    for (unsigned p = 1; p < 4; ++p)
      lds[p * LDSW + q] = (q + p < LDSW) ? lds[q + p] : 0.f;
  }
  __syncthreads();

  // ---- streaming outer-product stores
  const unsigned base = b * DD;            // dword base of this batch
  const unsigned c_lo = (base + 3u) >> 2;  // first full 16B chunk
  const unsigned c_hi = (base + DD) >> 2;  // one past last full chunk
  const unsigned nch  = c_hi - c_lo;
  const unsigned per  = (nch + (unsigned)NB - 1u) / (unsigned)NB;
  unsigned c     = c_lo + nb * per + t;
  unsigned c_end = c_lo + nb * per + per;
  if (c_end > c_hi) c_end = c_hi;

  for (; c < c_end; c += 256u) {
    const unsigned o = 4u * c - base;      // dword offset within batch
    const unsigned i = o / 1001u;          // row (magic-mul div)
    const unsigned j = o - i * 1001u;      // col of first dword
    vfloat4 vals;
    if (j <= 997u) {                       // chunk stays inside row i
      const float r = lds[i];              // 0 for pad rows (i>=784)
      if (r != 0.f && j < 784u) {
        const unsigned p = j & 3u;
        const unsigned m = j & ~3u;
        vfloat4 c4 = *(const vfloat4*)(lds + p * LDSW + m);  // ds_read_b128
        vals = c4 * r;
      } else {
        vals = (vfloat4){0.f, 0.f, 0.f, 0.f};
      }
    } else {                               // row-wrap chunk (~0.3%)
      float v[4];
      #pragma unroll
      for (unsigned k = 0; k < 4u; ++k) {
        unsigned jk = j + k;
        unsigned ik = i;
        if (jk >= 1001u) { jk -= 1001u; ik += 1u; }
        v[k] = lds[ik] * lds[jk];
      }
      vals = (vfloat4){v[0], v[1], v[2], v[3]};
    }
    *(vfloat4*)(out + 4u * c) = vals;
  }

  // batch-boundary scalar dwords (DD odd -> up to 3 head + 3 tail per batch)
  if (nb == 0u) {
    if (t == 0u) {
      const unsigned hb = (4u - (b & 3u)) & 3u;   // head dwords: row 0
      const float r0 = lds[0];
      for (unsigned k = 0; k < hb; ++k)
        out[base + k] = r0 * lds[k];
    } else if (t == 1u) {
      const unsigned tb = (b + 1u) & 3u;          // tail dwords: row 1000 (zeros)
      for (unsigned k = 0; k < tb; ++k)
        out[4u * c_hi + k] = 0.f;
    }
  }
}

extern "C" void kernel_launch(void* const* d_in, const int* in_sizes, int n_in,
                              void* d_out, int out_size, void* d_ws, size_t ws_size,
                              hipStream_t stream) {
  const float* x = (const float*)d_in[0];
  float* out = (float*)d_out;
  amp_fused_kernel<<<BATCH * NB, 256, 0, stream>>>(x, out);
}